// Round 19
// baseline (180.285 us; speedup 1.0000x reference)
//
#include <hip/hip_runtime.h>

typedef unsigned short u16;
typedef __attribute__((ext_vector_type(8))) unsigned short u16x8;
typedef __attribute__((ext_vector_type(2))) unsigned int u32x2;
typedef __attribute__((ext_vector_type(8))) __bf16 bf16x8;
typedef __attribute__((ext_vector_type(4))) float f32x4;

#define T_SEQ 2048
#define WINDOW 1024
// 0.125 * log2(e)
#define QSCALE 0.18033688011112042f

static __device__ __forceinline__ u16 f2bf(float f) {
    unsigned int u = __float_as_uint(f);
    u += 0x7fffu + ((u >> 16) & 1u);
    return (u16)(u >> 16);
}
static __device__ __forceinline__ bf16x8 ld_bf8(const u16* p) {
    return __builtin_bit_cast(bf16x8, *(const u16x8*)p);
}
static __device__ __forceinline__ unsigned int cvt_pk_bf16(float lo, float hi) {
    unsigned int r;
    asm("v_cvt_pk_bf16_f32 %0, %1, %2" : "=v"(r) : "v"(lo), "v"(hi));
    return r;
}
static __device__ __forceinline__ float exp2f_raw(float x) {
#if __has_builtin(__builtin_amdgcn_exp2f)
    return __builtin_amdgcn_exp2f(x);
#else
    return exp2f(x);
#endif
}
// async global -> LDS, 16B per lane (wave-uniform LDS base + lane*16)
static __device__ __forceinline__ void g2l16(const void* g, void* l) {
    __builtin_amdgcn_global_load_lds(
        (const __attribute__((address_space(1))) void*)g,
        (__attribute__((address_space(3))) void*)l, 16, 0, 0);
}

// per-CU work-balance permutation for attn q-tiles: quartets {a,a+4,a+8,a+12}
// map to tile-counts summing to exactly 54 each (see round-11 analysis)
__device__ const int q_tmap[16] = {0, 1, 2, 3, 7, 6, 5, 4, 8, 10, 12, 14, 9, 11, 13, 15};

// ---------------- RoPE cos/sin table: float2[2048][32] ----------------
__global__ __launch_bounds__(256)
void rope_tab_kernel(float2* __restrict__ tab)
{
    int idx = blockIdx.x * 256 + threadIdx.x;   // 65536
    int t = idx >> 5, dp = idx & 31;
    float inv_freq = __expf(-dp * 0.28782313662425574f); // ln(10000)/32
    float ang = (float)t * inv_freq;
    float s, c;
    sincosf(ang, &s, &c);
    tab[idx] = make_float2(c, s);
}

// ---------------- x fp32 -> bf16 (same layout) ----------------
__global__ __launch_bounds__(256)
void convert_x(const float* __restrict__ src, u16* __restrict__ dst)
{
    int i8 = blockIdx.x * 256 + threadIdx.x;
    size_t base = (size_t)i8 * 8;
    float4 a = *(const float4*)(src + base);
    float4 b = *(const float4*)(src + base + 4);
    u16x8 o = { f2bf(a.x), f2bf(a.y), f2bf(a.z), f2bf(a.w),
                f2bf(b.x), f2bf(b.y), f2bf(b.z), f2bf(b.w) };
    *(u16x8*)(dst + base) = o;
}

// ---------------- all W fp32 [2048][N] -> bf16 transposed [N][2048], scaled ----------------
__global__ __launch_bounds__(256)
void trans_conv_all(const float* __restrict__ Wq, const float* __restrict__ Wk,
                    const float* __restrict__ Wv, const float* __restrict__ Wo,
                    u16* __restrict__ WqkvT, u16* __restrict__ WoT)
{
    __shared__ __align__(16) u16 tile[64][72];
    const int z = blockIdx.z;
    const float* src; int N; float scale; u16* dst;
    if (z == 0)      { src = Wq; N = 2048; scale = QSCALE; dst = WqkvT; }
    else if (z == 1) { src = Wk; N = 512;  scale = 1.f;    dst = WqkvT + (size_t)2048 * 2048; }
    else if (z == 2) { src = Wv; N = 512;  scale = 1.f;    dst = WqkvT + (size_t)2560 * 2048; }
    else             { src = Wo; N = 2048; scale = 1.f;    dst = WoT; }
    if ((int)blockIdx.y * 64 >= N) return;

    const int tid = threadIdx.x;
    const int k0 = blockIdx.x * 64;
    const int n0 = blockIdx.y * 64;
    {
        int r = tid >> 2, c0 = (tid & 3) * 16;
        const float* sp = src + (size_t)(k0 + r) * N + n0 + c0;
        float4 v0 = *(const float4*)(sp + 0);
        float4 v1 = *(const float4*)(sp + 4);
        float4 v2 = *(const float4*)(sp + 8);
        float4 v3 = *(const float4*)(sp + 12);
        u16x8 s0 = { f2bf(v0.x * scale), f2bf(v0.y * scale), f2bf(v0.z * scale), f2bf(v0.w * scale),
                     f2bf(v1.x * scale), f2bf(v1.y * scale), f2bf(v1.z * scale), f2bf(v1.w * scale) };
        u16x8 s1 = { f2bf(v2.x * scale), f2bf(v2.y * scale), f2bf(v2.z * scale), f2bf(v2.w * scale),
                     f2bf(v3.x * scale), f2bf(v3.y * scale), f2bf(v3.z * scale), f2bf(v3.w * scale) };
        *(u16x8*)&tile[r][c0]     = s0;
        *(u16x8*)&tile[r][c0 + 8] = s1;
    }
    __syncthreads();
    {
        int n = tid >> 2, j0 = (tid & 3) * 16;
        u16x8 o0, o1;
        #pragma unroll
        for (int i = 0; i < 8; ++i) o0[i] = tile[j0 + i][n];
        #pragma unroll
        for (int i = 0; i < 8; ++i) o1[i] = tile[j0 + 8 + i][n];
        u16* dp = dst + (size_t)(n0 + n) * 2048 + k0 + j0;
        *(u16x8*)dp       = o0;
        *(u16x8*)(dp + 8) = o1;
    }
}

// ================= GEMM core: 256 threads (4 waves, 2x2), block 128x128 =================
// per-wave 64x64, BK=64, XOR-swizzled conflict-free LDS, g2l16 staging.
__device__ __forceinline__ void gemm_core_256(const u16* __restrict__ Ag,
                                              const u16* __restrict__ Bg,
                                              u16 (*Al)[64], u16 (*Bl)[64],
                                              int lane, int w, f32x4 acc[4][4])
{
    const int wm = w >> 1, wn = w & 1;
    const int r8 = lane >> 3;             // row-within-8 of staging
    const int cs = (lane & 7) ^ r8;       // inverse-swizzled source chunk
    // wave w stages rows [w*32, w*32+32) in 4 instructions of 8 rows
    const u16* ag = Ag + (size_t)(w * 32 + r8) * 2048 + cs * 8;
    const u16* bg = Bg + (size_t)(w * 32 + r8) * 2048 + cs * 8;
    const int fr = lane & 15;
    const int hq = lane >> 4;

    for (int kb = 0; kb < 2048; kb += 64) {
        #pragma unroll
        for (int j = 0; j < 4; ++j)
            g2l16(ag + (size_t)(j * 8) * 2048 + kb, &Al[w * 32 + j * 8][0]);
        #pragma unroll
        for (int j = 0; j < 4; ++j)
            g2l16(bg + (size_t)(j * 8) * 2048 + kb, &Bl[w * 32 + j * 8][0]);
        __syncthreads();

        #pragma unroll
        for (int kk = 0; kk < 2; ++kk) {
            bf16x8 af[4], bfn[4];
            #pragma unroll
            for (int m = 0; m < 4; ++m) {
                int row = wm * 64 + m * 16 + fr;
                int pc = (kk * 4 + hq) ^ (row & 7);
                af[m] = ld_bf8(&Al[row][pc * 8]);
            }
            #pragma unroll
            for (int n = 0; n < 4; ++n) {
                int row = wn * 64 + n * 16 + fr;
                int pc = (kk * 4 + hq) ^ (row & 7);
                bfn[n] = ld_bf8(&Bl[row][pc * 8]);
            }
            #pragma unroll
            for (int m = 0; m < 4; ++m)
                #pragma unroll
                for (int n = 0; n < 4; ++n)
                    acc[m][n] = __builtin_amdgcn_mfma_f32_16x16x32_bf16(af[m], bfn[n], acc[m][n], 0, 0, 0);
        }
        __syncthreads();
    }
}

// ---------------- QKV GEMM + fused RoPE epilogue + fused V transpose ----------------
__global__ __launch_bounds__(256, 3)
void qkv_gemm(const u16* __restrict__ xb, const u16* __restrict__ Wt,
              const float2* __restrict__ tab,
              u16* __restrict__ Qb, u16* __restrict__ Kb, u16* __restrict__ Vt)
{
    __shared__ __align__(16) u16 Al[128][64];
    __shared__ __align__(16) u16 Bl[128][64];
    const int tid = threadIdx.x;
    const int lane = tid & 63;
    const int w = tid >> 6;
    const int wm = w >> 1, wn = w & 1;
    const int m0  = blockIdx.x * 128;
    const int n0g = blockIdx.y * 128;

    f32x4 acc[4][4] = {};
    gemm_core_256(xb + (size_t)m0 * 2048, Wt + (size_t)n0g * 2048, Al, Bl, lane, w, acc);

    const int hq = lane >> 4;
    const int c0 = lane & 15;
    const int colbase = n0g + wn * 64;         // multiple of 64
    const bool isV = (n0g >= 2560);
    const bool isQ = (n0g < 2048);

    #pragma unroll
    for (int m = 0; m < 4; ++m) {
        #pragma unroll
        for (int r = 0; r < 4; ++r) {
            int rw = m0 + wm * 64 + m * 16 + hq * 4 + r;
            int b = rw >> 11, t = rw & 2047;
            if (!isV) {
                #pragma unroll
                for (int np = 0; np < 2; ++np) {
                    int dp = np * 16 + c0;
                    float2 cs = tab[t * 32 + dp];
                    float x1 = acc[m][np][r];
                    float x2 = acc[m][np + 2][r];
                    float lo = x1 * cs.x - x2 * cs.y;
                    float hi = x2 * cs.x + x1 * cs.y;
                    if (isQ) {
                        int h = colbase >> 6;
                        size_t base = (((size_t)b * 32 + h) * 2048 + t) * 64 + dp;
                        Qb[base]      = f2bf(lo);
                        Qb[base + 32] = f2bf(hi);
                    } else {
                        int hk = (colbase - 2048) >> 6;
                        size_t base = (((size_t)b * 8 + hk) * 2048 + t) * 64 + dp;
                        Kb[base]      = f2bf(lo);
                        Kb[base + 32] = f2bf(hi);
                    }
                }
            } else {
                // write V TRANSPOSED: Vt[(b,hk,d,t)] -- fuses the old vtrans kernel
                #pragma unroll
                for (int n = 0; n < 4; ++n) {
                    int c2 = colbase + n * 16 + c0 - 2560;
                    int hk = c2 >> 6, d = c2 & 63;
                    Vt[(((size_t)b * 8 + hk) * 64 + d) * 2048 + t] = f2bf(acc[m][n][r]);
                }
            }
        }
    }
}

// ---------------- Output projection ----------------
__global__ __launch_bounds__(256, 3)
void out_gemm(const u16* __restrict__ A, const u16* __restrict__ Wt, float* __restrict__ C)
{
    __shared__ __align__(16) u16 Al[128][64];
    __shared__ __align__(16) u16 Bl[128][64];
    const int tid = threadIdx.x;
    const int lane = tid & 63;
    const int w = tid >> 6;
    const int wm = w >> 1, wn = w & 1;
    const int m0 = blockIdx.x * 128;
    const int n0 = blockIdx.y * 128;

    f32x4 acc[4][4] = {};
    gemm_core_256(A + (size_t)m0 * 2048, Wt + (size_t)n0 * 2048, Al, Bl, lane, w, acc);

    const int hq = lane >> 4;
    const int c0 = lane & 15;
    #pragma unroll
    for (int m = 0; m < 4; ++m) {
        #pragma unroll
        for (int n = 0; n < 4; ++n) {
            #pragma unroll
            for (int r = 0; r < 4; ++r) {
                int rw = m0 + wm * 64 + m * 16 + hq * 4 + r;
                int col = n0 + wn * 64 + n * 16 + c0;
                C[(size_t)rw * 2048 + col] = acc[m][n][r];
            }
        }
    }
}

// ---------------- Flash attention: 8 waves, QBLK=128, CU-work-balanced grid ----------------
// (round-16 verified structure, byte-identical: reg-staged K/V prefetch, 2 barriers/tile,
//  s_setprio around MFMA clusters, vector row-max)
__global__ __launch_bounds__(512)
void attn_kernel(const u16* __restrict__ Qb, const u16* __restrict__ Kb,
                 const u16* __restrict__ Vt, u16* __restrict__ AO)
{
    __shared__ __align__(16) u16 Kl[64][64];    // XOR-swizzled 16B chunks
    __shared__ __align__(16) u16 Vl[64][64];    // Vl[d][j], swizzled
    __shared__ __align__(16) u16 Pl[8][16][64]; // per-wave [q][k], swizzled

    const int tid = threadIdx.x;
    const int lane = tid & 63;
    const int w = tid >> 6;                 // 0..7
    const int q = lane & 15;
    const int hq = lane >> 4;
    const int q0 = q_tmap[blockIdx.y] * 128;   // balanced q-tile per CU quartet
    const int bh = blockIdx.x;                 // bh fast -> CU quartets span q-tiles
    const int b = bh >> 5, h = bh & 31;
    const int hk = h >> 2;
    const size_t qbase  = (size_t)bh * 2048 * 64;
    const size_t kvbase = ((size_t)b * 8 + hk) * 2048 * 64;

    // staging: one 16B chunk per thread per array (512 thr = 64 rows x 8 chunks)
    const int sj = tid >> 3;                // row 0..63
    const int sc = tid & 7;                 // logical chunk
    const int sw = (sc ^ (sj & 7)) << 3;    // swizzled phys offset (u16 units)
    const int ca0 = ((hq    ) ^ (q & 7)) << 3;
    const int ca1 = ((hq + 4) ^ (q & 7)) << 3;

    bf16x8 qf0, qf1;
    {
        const u16* qp = Qb + qbase + (size_t)(q0 + w * 16 + q) * 64 + hq * 8;
        qf0 = ld_bf8(qp);
        qf1 = ld_bf8(qp + 32);
    }

    float mrun = -1e20f, lrun = 0.f;
    f32x4 o[4] = {};

    int kbeg = q0 - (WINDOW - 1);
    if (kbeg < 0) kbeg = 0;
    kbeg &= ~63;
    const int kend = q0 + 128;

    const int wrow_min = q0 + w * 16;
    const int wrow_max = wrow_min + 15;
    const int iq = wrow_min + q;

    u16x8 kr, vr;
    {
        const u16* kg = Kb + kvbase + (size_t)(kbeg + sj) * 64 + sc * 8;
        kr = *(const u16x8*)kg;
        const u16* vg = Vt + kvbase + (size_t)sj * 2048 + kbeg + sc * 8;
        vr = *(const u16x8*)vg;
    }
    *(u16x8*)&Kl[sj][sw] = kr;
    *(u16x8*)&Vl[sj][sw] = vr;
    __syncthreads();

    for (int k0 = kbeg; k0 < kend; k0 += 64) {
        const bool has_next = (k0 + 64 < kend);
        if (has_next) {
            const u16* kg = Kb + kvbase + (size_t)(k0 + 64 + sj) * 64 + sc * 8;
            kr = *(const u16x8*)kg;
            const u16* vg = Vt + kvbase + (size_t)sj * 2048 + k0 + 64 + sc * 8;
            vr = *(const u16x8*)vg;
        }

        bool active = (k0 <= wrow_max) && (k0 + 63 >= wrow_min - (WINDOW - 1));
        if (active) {
            f32x4 s[4];
            __builtin_amdgcn_s_setprio(1);
            #pragma unroll
            for (int nf = 0; nf < 4; ++nf) {
                bf16x8 kb0 = ld_bf8(&Kl[nf * 16 + q][ca0]);
                bf16x8 kb1 = ld_bf8(&Kl[nf * 16 + q][ca1]);
                f32x4 a = {};
                a = __builtin_amdgcn_mfma_f32_16x16x32_bf16(kb0, qf0, a, 0, 0, 0);
                a = __builtin_amdgcn_mfma_f32_16x16x32_bf16(kb1, qf1, a, 0, 0, 0);
                s[nf] = a;
            }
            __builtin_amdgcn_s_setprio(0);
            bool need_causal = (k0 + 63 > wrow_min);
            bool need_window = (wrow_max - k0) >= WINDOW;
            if (need_causal || need_window) {
                #pragma unroll
                for (int nf = 0; nf < 4; ++nf) {
                    #pragma unroll
                    for (int r = 0; r < 4; ++r) {
                        int j = k0 + nf * 16 + hq * 4 + r;
                        bool ok = (j <= iq) && (iq - j < WINDOW);
                        if (!ok) s[nf][r] = -1e30f;
                    }
                }
            }
            f32x4 m4 = __builtin_elementwise_max(
                __builtin_elementwise_max(s[0], s[1]),
                __builtin_elementwise_max(s[2], s[3]));
            float tmax = fmaxf(fmaxf(m4[0], m4[1]), fmaxf(m4[2], m4[3]));
            tmax = fmaxf(tmax, __shfl_xor(tmax, 16));
            tmax = fmaxf(tmax, __shfl_xor(tmax, 32));

            bool skip = __all(tmax <= mrun + 11.5f);
            float mnew = skip ? mrun : fmaxf(mrun, tmax);

            float tsum = 0.f;
            #pragma unroll
            for (int nf = 0; nf < 4; ++nf) {
                float p0 = exp2f_raw(s[nf][0] - mnew);
                float p1 = exp2f_raw(s[nf][1] - mnew);
                float p2 = exp2f_raw(s[nf][2] - mnew);
                float p3 = exp2f_raw(s[nf][3] - mnew);
                tsum += (p0 + p1) + (p2 + p3);
                u32x2 pw = { cvt_pk_bf16(p0, p1), cvt_pk_bf16(p2, p3) };
                int cpw = (((2 * nf + (hq >> 1)) ^ (q & 7)) << 3) + ((hq & 1) << 2);
                *(u32x2*)&Pl[w][q][cpw] = pw;
            }
            tsum += __shfl_xor(tsum, 16);
            tsum += __shfl_xor(tsum, 32);

            if (skip) {
                lrun += tsum;
            } else {
                float sc2 = exp2f_raw(mrun - mnew);
                mrun = mnew;
                lrun = lrun * sc2 + tsum;
                float osc[4];
                #pragma unroll
                for (int r = 0; r < 4; ++r)
                    osc[r] = __shfl(sc2, (lane & 48) + hq * 4 + r);
                #pragma unroll
                for (int nf = 0; nf < 4; ++nf)
                    #pragma unroll
                    for (int r = 0; r < 4; ++r)
                        o[nf][r] *= osc[r];
            }

            bf16x8 pa0 = ld_bf8(&Pl[w][q][ca0]);
            bf16x8 pa1 = ld_bf8(&Pl[w][q][ca1]);
            __builtin_amdgcn_s_setprio(1);
            #pragma unroll
            for (int nf = 0; nf < 4; ++nf) {
                bf16x8 vb0 = ld_bf8(&Vl[nf * 16 + q][ca0]);
                bf16x8 vb1 = ld_bf8(&Vl[nf * 16 + q][ca1]);
                o[nf] = __builtin_amdgcn_mfma_f32_16x16x32_bf16(pa0, vb0, o[nf], 0, 0, 0);
                o[nf] = __builtin_amdgcn_mfma_f32_16x16x32_bf16(pa1, vb1, o[nf], 0, 0, 0);
            }
            __builtin_amdgcn_s_setprio(0);
        }
        __syncthreads();
        if (has_next) {
            *(u16x8*)&Kl[sj][sw] = kr;
            *(u16x8*)&Vl[sj][sw] = vr;
        }
        __syncthreads();
    }

    float linv_own = 1.f / lrun;
    float linv[4];
    #pragma unroll
    for (int r = 0; r < 4; ++r)
        linv[r] = __shfl(linv_own, (lane & 48) + hq * 4 + r);
    #pragma unroll
    for (int nf = 0; nf < 4; ++nf) {
        #pragma unroll
        for (int r = 0; r < 4; ++r) {
            int i = q0 + w * 16 + hq * 4 + r;
            int d = nf * 16 + q;
            AO[((size_t)b * 2048 + i) * 2048 + h * 64 + d] = f2bf(o[nf][r] * linv[r]);
        }
    }
}

extern "C" void kernel_launch(void* const* d_in, const int* in_sizes, int n_in,
                              void* d_out, int out_size, void* d_ws, size_t ws_size,
                              hipStream_t stream)
{
    const float* x  = (const float*)d_in[0];
    const float* Wq = (const float*)d_in[1];
    const float* Wk = (const float*)d_in[2];
    const float* Wv = (const float*)d_in[3];
    const float* Wo = (const float*)d_in[4];
    float* out = (float*)d_out;

    u16* Qb    = (u16*)d_ws;                              //  8,388,608
    u16* Kb    = Qb    + (size_t)8388608;                 //  2,097,152
    u16* Vt    = Kb    + (size_t)2097152;                 //  2,097,152  (b,hk,d,t)
    u16* AO    = Vt    + (size_t)2097152;                 //  8,388,608
    u16* xb    = AO    + (size_t)8388608;                 //  8,388,608
    u16* WqkvT = xb    + (size_t)8388608;                 //  6,291,456  [3072][2048]
    u16* WoT   = WqkvT + (size_t)6291456;                 //  4,194,304  [2048][2048]
    float2* tab = (float2*)(WoT + (size_t)4194304);       //  512KB

    rope_tab_kernel<<<256, 256, 0, stream>>>(tab);
    convert_x<<<4096, 256, 0, stream>>>(x, xb);
    trans_conv_all<<<dim3(32, 32, 4), 256, 0, stream>>>(Wq, Wk, Wv, Wo, WqkvT, WoT);

    qkv_gemm<<<dim3(32, 24), 256, 0, stream>>>(xb, WqkvT, tab, Qb, Kb, Vt);
    attn_kernel<<<dim3(64, 16), 512, 0, stream>>>(Qb, Kb, Vt, AO);
    out_gemm<<<dim3(32, 16), 256, 0, stream>>>(AO, WoT, out);
}

// Round 20
// 173.691 us; speedup vs baseline: 1.0380x; 1.0380x over previous
//
#include <hip/hip_runtime.h>

typedef unsigned short u16;
typedef __attribute__((ext_vector_type(4))) unsigned short u16x4v;
typedef __attribute__((ext_vector_type(8))) unsigned short u16x8;
typedef __attribute__((ext_vector_type(2))) unsigned int u32x2;
typedef __attribute__((ext_vector_type(8))) __bf16 bf16x8;
typedef __attribute__((ext_vector_type(4))) float f32x4;

#define T_SEQ 2048
#define WINDOW 1024
// 0.125 * log2(e)
#define QSCALE 0.18033688011112042f

static __device__ __forceinline__ u16 f2bf(float f) {
    unsigned int u = __float_as_uint(f);
    u += 0x7fffu + ((u >> 16) & 1u);
    return (u16)(u >> 16);
}
static __device__ __forceinline__ bf16x8 ld_bf8(const u16* p) {
    return __builtin_bit_cast(bf16x8, *(const u16x8*)p);
}
static __device__ __forceinline__ unsigned int cvt_pk_bf16(float lo, float hi) {
    unsigned int r;
    asm("v_cvt_pk_bf16_f32 %0, %1, %2" : "=v"(r) : "v"(lo), "v"(hi));
    return r;
}
static __device__ __forceinline__ float exp2f_raw(float x) {
#if __has_builtin(__builtin_amdgcn_exp2f)
    return __builtin_amdgcn_exp2f(x);
#else
    return exp2f(x);
#endif
}
// async global -> LDS, 16B per lane (wave-uniform LDS base + lane*16)
static __device__ __forceinline__ void g2l16(const void* g, void* l) {
    __builtin_amdgcn_global_load_lds(
        (const __attribute__((address_space(1))) void*)g,
        (__attribute__((address_space(3))) void*)l, 16, 0, 0);
}

// per-CU work-balance permutation for attn q-tiles: quartets {a,a+4,a+8,a+12}
// map to tile-counts summing to exactly 54 each (see round-11 analysis)
__device__ const int q_tmap[16] = {0, 1, 2, 3, 7, 6, 5, 4, 8, 10, 12, 14, 9, 11, 13, 15};

// ---------------- x fp32 -> bf16 (same layout) ----------------
__global__ __launch_bounds__(256)
void convert_x(const float* __restrict__ src, u16* __restrict__ dst)
{
    int i8 = blockIdx.x * 256 + threadIdx.x;
    size_t base = (size_t)i8 * 8;
    float4 a = *(const float4*)(src + base);
    float4 b = *(const float4*)(src + base + 4);
    u16x8 o = { f2bf(a.x), f2bf(a.y), f2bf(a.z), f2bf(a.w),
                f2bf(b.x), f2bf(b.y), f2bf(b.z), f2bf(b.w) };
    *(u16x8*)(dst + base) = o;
}

// ---------------- all W fp32 [2048][N] -> bf16 transposed [N][2048], scaled ----------------
// z == 4: RoPE cos/sin table float2[2048][32] (first 256 (x,y) blocks)
__global__ __launch_bounds__(256)
void trans_conv_all(const float* __restrict__ Wq, const float* __restrict__ Wk,
                    const float* __restrict__ Wv, const float* __restrict__ Wo,
                    u16* __restrict__ WqkvT, u16* __restrict__ WoT,
                    float2* __restrict__ tab)
{
    const int z = blockIdx.z;
    if (z == 4) {
        int blk = blockIdx.y * 32 + blockIdx.x;
        if (blk >= 256) return;
        int idx = blk * 256 + threadIdx.x;     // 65536
        int t = idx >> 5, dp = idx & 31;
        float inv_freq = __expf(-dp * 0.28782313662425574f); // ln(10000)/32
        float ang = (float)t * inv_freq;
        float s, c;
        sincosf(ang, &s, &c);
        tab[idx] = make_float2(c, s);
        return;
    }

    __shared__ __align__(16) u16 tile[64][72];
    const float* src; int N; float scale; u16* dst;
    if (z == 0)      { src = Wq; N = 2048; scale = QSCALE; dst = WqkvT; }
    else if (z == 1) { src = Wk; N = 512;  scale = 1.f;    dst = WqkvT + (size_t)2048 * 2048; }
    else if (z == 2) { src = Wv; N = 512;  scale = 1.f;    dst = WqkvT + (size_t)2560 * 2048; }
    else             { src = Wo; N = 2048; scale = 1.f;    dst = WoT; }
    if ((int)blockIdx.y * 64 >= N) return;

    const int tid = threadIdx.x;
    const int k0 = blockIdx.x * 64;
    const int n0 = blockIdx.y * 64;
    {
        int r = tid >> 2, c0 = (tid & 3) * 16;
        const float* sp = src + (size_t)(k0 + r) * N + n0 + c0;
        float4 v0 = *(const float4*)(sp + 0);
        float4 v1 = *(const float4*)(sp + 4);
        float4 v2 = *(const float4*)(sp + 8);
        float4 v3 = *(const float4*)(sp + 12);
        u16x8 s0 = { f2bf(v0.x * scale), f2bf(v0.y * scale), f2bf(v0.z * scale), f2bf(v0.w * scale),
                     f2bf(v1.x * scale), f2bf(v1.y * scale), f2bf(v1.z * scale), f2bf(v1.w * scale) };
        u16x8 s1 = { f2bf(v2.x * scale), f2bf(v2.y * scale), f2bf(v2.z * scale), f2bf(v2.w * scale),
                     f2bf(v3.x * scale), f2bf(v3.y * scale), f2bf(v3.z * scale), f2bf(v3.w * scale) };
        *(u16x8*)&tile[r][c0]     = s0;
        *(u16x8*)&tile[r][c0 + 8] = s1;
    }
    __syncthreads();
    {
        int n = tid >> 2, j0 = (tid & 3) * 16;
        u16x8 o0, o1;
        #pragma unroll
        for (int i = 0; i < 8; ++i) o0[i] = tile[j0 + i][n];
        #pragma unroll
        for (int i = 0; i < 8; ++i) o1[i] = tile[j0 + 8 + i][n];
        u16* dp = dst + (size_t)(n0 + n) * 2048 + k0 + j0;
        *(u16x8*)dp       = o0;
        *(u16x8*)(dp + 8) = o1;
    }
}

// ================= GEMM core: 256 threads (4 waves, 2x2), block 128x128 =================
// per-wave 64x64, BK=64, XOR-swizzled conflict-free LDS, g2l16 staging.
__device__ __forceinline__ void gemm_core_256(const u16* __restrict__ Ag,
                                              const u16* __restrict__ Bg,
                                              u16 (*Al)[64], u16 (*Bl)[64],
                                              int lane, int w, f32x4 acc[4][4])
{
    const int wm = w >> 1, wn = w & 1;
    const int r8 = lane >> 3;             // row-within-8 of staging
    const int cs = (lane & 7) ^ r8;       // inverse-swizzled source chunk
    // wave w stages rows [w*32, w*32+32) in 4 instructions of 8 rows
    const u16* ag = Ag + (size_t)(w * 32 + r8) * 2048 + cs * 8;
    const u16* bg = Bg + (size_t)(w * 32 + r8) * 2048 + cs * 8;
    const int fr = lane & 15;
    const int hq = lane >> 4;

    for (int kb = 0; kb < 2048; kb += 64) {
        #pragma unroll
        for (int j = 0; j < 4; ++j)
            g2l16(ag + (size_t)(j * 8) * 2048 + kb, &Al[w * 32 + j * 8][0]);
        #pragma unroll
        for (int j = 0; j < 4; ++j)
            g2l16(bg + (size_t)(j * 8) * 2048 + kb, &Bl[w * 32 + j * 8][0]);
        __syncthreads();

        #pragma unroll
        for (int kk = 0; kk < 2; ++kk) {
            bf16x8 af[4], bfn[4];
            #pragma unroll
            for (int m = 0; m < 4; ++m) {
                int row = wm * 64 + m * 16 + fr;
                int pc = (kk * 4 + hq) ^ (row & 7);
                af[m] = ld_bf8(&Al[row][pc * 8]);
            }
            #pragma unroll
            for (int n = 0; n < 4; ++n) {
                int row = wn * 64 + n * 16 + fr;
                int pc = (kk * 4 + hq) ^ (row & 7);
                bfn[n] = ld_bf8(&Bl[row][pc * 8]);
            }
            #pragma unroll
            for (int m = 0; m < 4; ++m)
                #pragma unroll
                for (int n = 0; n < 4; ++n)
                    acc[m][n] = __builtin_amdgcn_mfma_f32_16x16x32_bf16(af[m], bfn[n], acc[m][n], 0, 0, 0);
        }
        __syncthreads();
    }
}

// ---------------- QKV GEMM + fused RoPE epilogue + fused V transpose ----------------
__global__ __launch_bounds__(256, 3)
void qkv_gemm(const u16* __restrict__ xb, const u16* __restrict__ Wt,
              const float2* __restrict__ tab,
              u16* __restrict__ Qb, u16* __restrict__ Kb, u16* __restrict__ Vt)
{
    __shared__ __align__(16) u16 Al[128][64];
    __shared__ __align__(16) u16 Bl[128][64];
    const int tid = threadIdx.x;
    const int lane = tid & 63;
    const int w = tid >> 6;
    const int wm = w >> 1, wn = w & 1;
    const int m0  = blockIdx.x * 128;
    const int n0g = blockIdx.y * 128;

    f32x4 acc[4][4] = {};
    gemm_core_256(xb + (size_t)m0 * 2048, Wt + (size_t)n0g * 2048, Al, Bl, lane, w, acc);

    const int hq = lane >> 4;
    const int c0 = lane & 15;
    const int colbase = n0g + wn * 64;         // multiple of 64
    const bool isV = (n0g >= 2560);
    const bool isQ = (n0g < 2048);

    #pragma unroll
    for (int m = 0; m < 4; ++m) {
        #pragma unroll
        for (int r = 0; r < 4; ++r) {
            int rw = m0 + wm * 64 + m * 16 + hq * 4 + r;
            int b = rw >> 11, t = rw & 2047;
            if (!isV) {
                #pragma unroll
                for (int np = 0; np < 2; ++np) {
                    int dp = np * 16 + c0;
                    float2 cs = tab[t * 32 + dp];
                    float x1 = acc[m][np][r];
                    float x2 = acc[m][np + 2][r];
                    float lo = x1 * cs.x - x2 * cs.y;
                    float hi = x2 * cs.x + x1 * cs.y;
                    if (isQ) {
                        int h = colbase >> 6;
                        size_t base = (((size_t)b * 32 + h) * 2048 + t) * 64 + dp;
                        Qb[base]      = f2bf(lo);
                        Qb[base + 32] = f2bf(hi);
                    } else {
                        int hk = (colbase - 2048) >> 6;
                        size_t base = (((size_t)b * 8 + hk) * 2048 + t) * 64 + dp;
                        Kb[base]      = f2bf(lo);
                        Kb[base + 32] = f2bf(hi);
                    }
                }
            } else {
                // write V TRANSPOSED: Vt[(b,hk,d,t)] -- fuses the old vtrans kernel
                #pragma unroll
                for (int n = 0; n < 4; ++n) {
                    int c2 = colbase + n * 16 + c0 - 2560;
                    int hk = c2 >> 6, d = c2 & 63;
                    Vt[(((size_t)b * 8 + hk) * 64 + d) * 2048 + t] = f2bf(acc[m][n][r]);
                }
            }
        }
    }
}

// ---------------- Output projection ----------------
__global__ __launch_bounds__(256, 3)
void out_gemm(const u16* __restrict__ A, const u16* __restrict__ Wt, float* __restrict__ C)
{
    __shared__ __align__(16) u16 Al[128][64];
    __shared__ __align__(16) u16 Bl[128][64];
    const int tid = threadIdx.x;
    const int lane = tid & 63;
    const int w = tid >> 6;
    const int wm = w >> 1, wn = w & 1;
    const int m0 = blockIdx.x * 128;
    const int n0 = blockIdx.y * 128;

    f32x4 acc[4][4] = {};
    gemm_core_256(A + (size_t)m0 * 2048, Wt + (size_t)n0 * 2048, Al, Bl, lane, w, acc);

    const int hq = lane >> 4;
    const int c0 = lane & 15;
    #pragma unroll
    for (int m = 0; m < 4; ++m) {
        #pragma unroll
        for (int n = 0; n < 4; ++n) {
            #pragma unroll
            for (int r = 0; r < 4; ++r) {
                int rw = m0 + wm * 64 + m * 16 + hq * 4 + r;
                int col = n0 + wn * 64 + n * 16 + c0;
                C[(size_t)rw * 2048 + col] = acc[m][n][r];
            }
        }
    }
}

// ---------------- Flash attention: 8 waves, QBLK=128, CU-work-balanced grid ----------------
// round-16 verified sync structure (reg-staged K/V prefetch, 2 barriers/tile).
// PV computed SWAPPED: o[nf] = mfma(vb, pa, o) -> o[nf][r] = O[q=lane&15][nf*16+hq*4+r];
// softmax stats owner q == O row owner -> no osc/linv shuffles; vectorized AO stores.
__global__ __launch_bounds__(512)
void attn_kernel(const u16* __restrict__ Qb, const u16* __restrict__ Kb,
                 const u16* __restrict__ Vt, u16* __restrict__ AO)
{
    __shared__ __align__(16) u16 Kl[64][64];    // XOR-swizzled 16B chunks
    __shared__ __align__(16) u16 Vl[64][64];    // Vl[d][j], swizzled
    __shared__ __align__(16) u16 Pl[8][16][64]; // per-wave [q][k], swizzled

    const int tid = threadIdx.x;
    const int lane = tid & 63;
    const int w = tid >> 6;                 // 0..7
    const int q = lane & 15;
    const int hq = lane >> 4;
    const int q0 = q_tmap[blockIdx.y] * 128;   // balanced q-tile per CU quartet
    const int bh = blockIdx.x;                 // bh fast -> CU quartets span q-tiles
    const int b = bh >> 5, h = bh & 31;
    const int hk = h >> 2;
    const size_t qbase  = (size_t)bh * 2048 * 64;
    const size_t kvbase = ((size_t)b * 8 + hk) * 2048 * 64;

    // staging: one 16B chunk per thread per array (512 thr = 64 rows x 8 chunks)
    const int sj = tid >> 3;                // row 0..63
    const int sc = tid & 7;                 // logical chunk
    const int sw = (sc ^ (sj & 7)) << 3;    // swizzled phys offset (u16 units)
    const int ca0 = ((hq    ) ^ (q & 7)) << 3;
    const int ca1 = ((hq + 4) ^ (q & 7)) << 3;

    bf16x8 qf0, qf1;
    {
        const u16* qp = Qb + qbase + (size_t)(q0 + w * 16 + q) * 64 + hq * 8;
        qf0 = ld_bf8(qp);
        qf1 = ld_bf8(qp + 32);
    }

    float mrun = -1e20f, lrun = 0.f;
    f32x4 o[4] = {};

    int kbeg = q0 - (WINDOW - 1);
    if (kbeg < 0) kbeg = 0;
    kbeg &= ~63;
    const int kend = q0 + 128;

    const int wrow_min = q0 + w * 16;
    const int wrow_max = wrow_min + 15;
    const int iq = wrow_min + q;

    u16x8 kr, vr;
    {
        const u16* kg = Kb + kvbase + (size_t)(kbeg + sj) * 64 + sc * 8;
        kr = *(const u16x8*)kg;
        const u16* vg = Vt + kvbase + (size_t)sj * 2048 + kbeg + sc * 8;
        vr = *(const u16x8*)vg;
    }
    *(u16x8*)&Kl[sj][sw] = kr;
    *(u16x8*)&Vl[sj][sw] = vr;
    __syncthreads();

    for (int k0 = kbeg; k0 < kend; k0 += 64) {
        const bool has_next = (k0 + 64 < kend);
        if (has_next) {
            const u16* kg = Kb + kvbase + (size_t)(k0 + 64 + sj) * 64 + sc * 8;
            kr = *(const u16x8*)kg;
            const u16* vg = Vt + kvbase + (size_t)sj * 2048 + k0 + 64 + sc * 8;
            vr = *(const u16x8*)vg;
        }

        bool active = (k0 <= wrow_max) && (k0 + 63 >= wrow_min - (WINDOW - 1));
        if (active) {
            f32x4 s[4];
            __builtin_amdgcn_s_setprio(1);
            #pragma unroll
            for (int nf = 0; nf < 4; ++nf) {
                bf16x8 kb0 = ld_bf8(&Kl[nf * 16 + q][ca0]);
                bf16x8 kb1 = ld_bf8(&Kl[nf * 16 + q][ca1]);
                f32x4 a = {};
                a = __builtin_amdgcn_mfma_f32_16x16x32_bf16(kb0, qf0, a, 0, 0, 0);
                a = __builtin_amdgcn_mfma_f32_16x16x32_bf16(kb1, qf1, a, 0, 0, 0);
                s[nf] = a;
            }
            __builtin_amdgcn_s_setprio(0);
            bool need_causal = (k0 + 63 > wrow_min);
            bool need_window = (wrow_max - k0) >= WINDOW;
            if (need_causal || need_window) {
                #pragma unroll
                for (int nf = 0; nf < 4; ++nf) {
                    #pragma unroll
                    for (int r = 0; r < 4; ++r) {
                        int j = k0 + nf * 16 + hq * 4 + r;
                        bool ok = (j <= iq) && (iq - j < WINDOW);
                        if (!ok) s[nf][r] = -1e30f;
                    }
                }
            }
            f32x4 m4 = __builtin_elementwise_max(
                __builtin_elementwise_max(s[0], s[1]),
                __builtin_elementwise_max(s[2], s[3]));
            float tmax = fmaxf(fmaxf(m4[0], m4[1]), fmaxf(m4[2], m4[3]));
            tmax = fmaxf(tmax, __shfl_xor(tmax, 16));
            tmax = fmaxf(tmax, __shfl_xor(tmax, 32));

            bool skip = __all(tmax <= mrun + 11.5f);
            float mnew = skip ? mrun : fmaxf(mrun, tmax);

            float tsum = 0.f;
            #pragma unroll
            for (int nf = 0; nf < 4; ++nf) {
                float p0 = exp2f_raw(s[nf][0] - mnew);
                float p1 = exp2f_raw(s[nf][1] - mnew);
                float p2 = exp2f_raw(s[nf][2] - mnew);
                float p3 = exp2f_raw(s[nf][3] - mnew);
                tsum += (p0 + p1) + (p2 + p3);
                u32x2 pw = { cvt_pk_bf16(p0, p1), cvt_pk_bf16(p2, p3) };
                int cpw = (((2 * nf + (hq >> 1)) ^ (q & 7)) << 3) + ((hq & 1) << 2);
                *(u32x2*)&Pl[w][q][cpw] = pw;
            }
            tsum += __shfl_xor(tsum, 16);
            tsum += __shfl_xor(tsum, 32);

            if (skip) {
                lrun += tsum;
            } else {
                float sc2 = exp2f_raw(mrun - mnew);
                mrun = mnew;
                lrun = lrun * sc2 + tsum;
                // O rows are owned by q = lane&15 == stats owner: uniform scale, no shuffles
                #pragma unroll
                for (int nf = 0; nf < 4; ++nf)
                    #pragma unroll
                    for (int r = 0; r < 4; ++r)
                        o[nf][r] *= sc2;
            }

            bf16x8 pa0 = ld_bf8(&Pl[w][q][ca0]);
            bf16x8 pa1 = ld_bf8(&Pl[w][q][ca1]);
            __builtin_amdgcn_s_setprio(1);
            #pragma unroll
            for (int nf = 0; nf < 4; ++nf) {
                bf16x8 vb0 = ld_bf8(&Vl[nf * 16 + q][ca0]);
                bf16x8 vb1 = ld_bf8(&Vl[nf * 16 + q][ca1]);
                // SWAPPED: o[nf][r] = O^T[d=nf*16+hq*4+r][q] = O[q][nf*16+hq*4+r]
                o[nf] = __builtin_amdgcn_mfma_f32_16x16x32_bf16(vb0, pa0, o[nf], 0, 0, 0);
                o[nf] = __builtin_amdgcn_mfma_f32_16x16x32_bf16(vb1, pa1, o[nf], 0, 0, 0);
            }
            __builtin_amdgcn_s_setprio(0);
        }
        __syncthreads();
        if (has_next) {
            *(u16x8*)&Kl[sj][sw] = kr;
            *(u16x8*)&Vl[sj][sw] = vr;
        }
        __syncthreads();
    }

    // epilogue: lane-local l; 4 contiguous d per nf -> u16x4 stores
    float linv = 1.f / lrun;
    const int i = q0 + w * 16 + q;
    u16* aorow = AO + ((size_t)b * 2048 + i) * 2048 + h * 64;
    #pragma unroll
    for (int nf = 0; nf < 4; ++nf) {
        u16x4v ov = { f2bf(o[nf][0] * linv), f2bf(o[nf][1] * linv),
                      f2bf(o[nf][2] * linv), f2bf(o[nf][3] * linv) };
        *(u16x4v*)(aorow + nf * 16 + hq * 4) = ov;
    }
}

extern "C" void kernel_launch(void* const* d_in, const int* in_sizes, int n_in,
                              void* d_out, int out_size, void* d_ws, size_t ws_size,
                              hipStream_t stream)
{
    const float* x  = (const float*)d_in[0];
    const float* Wq = (const float*)d_in[1];
    const float* Wk = (const float*)d_in[2];
    const float* Wv = (const float*)d_in[3];
    const float* Wo = (const float*)d_in[4];
    float* out = (float*)d_out;

    u16* Qb    = (u16*)d_ws;                              //  8,388,608
    u16* Kb    = Qb    + (size_t)8388608;                 //  2,097,152
    u16* Vt    = Kb    + (size_t)2097152;                 //  2,097,152  (b,hk,d,t)
    u16* AO    = Vt    + (size_t)2097152;                 //  8,388,608
    u16* xb    = AO    + (size_t)8388608;                 //  8,388,608
    u16* WqkvT = xb    + (size_t)8388608;                 //  6,291,456  [3072][2048]
    u16* WoT   = WqkvT + (size_t)6291456;                 //  4,194,304  [2048][2048]
    float2* tab = (float2*)(WoT + (size_t)4194304);       //  512KB

    convert_x<<<4096, 256, 0, stream>>>(x, xb);
    trans_conv_all<<<dim3(32, 32, 5), 256, 0, stream>>>(Wq, Wk, Wv, Wo, WqkvT, WoT, tab);

    qkv_gemm<<<dim3(32, 24), 256, 0, stream>>>(xb, WqkvT, tab, Qb, Kb, Vt);
    attn_kernel<<<dim3(64, 16), 512, 0, stream>>>(Qb, Kb, Vt, AO);
    out_gemm<<<dim3(32, 16), 256, 0, stream>>>(AO, WoT, out);
}

// Round 21
// 170.066 us; speedup vs baseline: 1.0601x; 1.0213x over previous
//
#include <hip/hip_runtime.h>

typedef unsigned short u16;
typedef __attribute__((ext_vector_type(4))) unsigned short u16x4v;
typedef __attribute__((ext_vector_type(8))) unsigned short u16x8;
typedef __attribute__((ext_vector_type(2))) unsigned int u32x2;
typedef __attribute__((ext_vector_type(8))) __bf16 bf16x8;
typedef __attribute__((ext_vector_type(4))) float f32x4;

#define T_SEQ 2048
#define WINDOW 1024
// 0.125 * log2(e)
#define QSCALE 0.18033688011112042f

static __device__ __forceinline__ u16 f2bf(float f) {
    unsigned int u = __float_as_uint(f);
    u += 0x7fffu + ((u >> 16) & 1u);
    return (u16)(u >> 16);
}
static __device__ __forceinline__ bf16x8 ld_bf8(const u16* p) {
    return __builtin_bit_cast(bf16x8, *(const u16x8*)p);
}
static __device__ __forceinline__ unsigned int cvt_pk_bf16(float lo, float hi) {
    unsigned int r;
    asm("v_cvt_pk_bf16_f32 %0, %1, %2" : "=v"(r) : "v"(lo), "v"(hi));
    return r;
}
static __device__ __forceinline__ float exp2f_raw(float x) {
#if __has_builtin(__builtin_amdgcn_exp2f)
    return __builtin_amdgcn_exp2f(x);
#else
    return exp2f(x);
#endif
}
// async global -> LDS, 16B per lane (wave-uniform LDS base + lane*16)
static __device__ __forceinline__ void g2l16(const void* g, void* l) {
    __builtin_amdgcn_global_load_lds(
        (const __attribute__((address_space(1))) void*)g,
        (__attribute__((address_space(3))) void*)l, 16, 0, 0);
}

// per-CU work-balance permutation for attn q-tiles: quartets {a,a+4,a+8,a+12}
// map to tile-counts summing to exactly 54 each (see round-11 analysis)
__device__ const int q_tmap[16] = {0, 1, 2, 3, 7, 6, 5, 4, 8, 10, 12, 14, 9, 11, 13, 15};

// ---------------- x fp32 -> bf16 (same layout) ----------------
__global__ __launch_bounds__(256)
void convert_x(const float* __restrict__ src, u16* __restrict__ dst)
{
    int i8 = blockIdx.x * 256 + threadIdx.x;
    size_t base = (size_t)i8 * 8;
    float4 a = *(const float4*)(src + base);
    float4 b = *(const float4*)(src + base + 4);
    u16x8 o = { f2bf(a.x), f2bf(a.y), f2bf(a.z), f2bf(a.w),
                f2bf(b.x), f2bf(b.y), f2bf(b.z), f2bf(b.w) };
    *(u16x8*)(dst + base) = o;
}

// ---------------- all W fp32 [2048][N] -> bf16 transposed [N][2048], scaled ----------------
// z == 4: RoPE cos/sin table float2[2048][32] (first 256 (x,y) blocks)
__global__ __launch_bounds__(256)
void trans_conv_all(const float* __restrict__ Wq, const float* __restrict__ Wk,
                    const float* __restrict__ Wv, const float* __restrict__ Wo,
                    u16* __restrict__ WqkvT, u16* __restrict__ WoT,
                    float2* __restrict__ tab)
{
    const int z = blockIdx.z;
    if (z == 4) {
        int blk = blockIdx.y * 32 + blockIdx.x;
        if (blk >= 256) return;
        int idx = blk * 256 + threadIdx.x;     // 65536
        int t = idx >> 5, dp = idx & 31;
        float inv_freq = __expf(-dp * 0.28782313662425574f); // ln(10000)/32
        float ang = (float)t * inv_freq;
        float s, c;
        sincosf(ang, &s, &c);
        tab[idx] = make_float2(c, s);
        return;
    }

    __shared__ __align__(16) u16 tile[64][72];
    const float* src; int N; float scale; u16* dst;
    if (z == 0)      { src = Wq; N = 2048; scale = QSCALE; dst = WqkvT; }
    else if (z == 1) { src = Wk; N = 512;  scale = 1.f;    dst = WqkvT + (size_t)2048 * 2048; }
    else if (z == 2) { src = Wv; N = 512;  scale = 1.f;    dst = WqkvT + (size_t)2560 * 2048; }
    else             { src = Wo; N = 2048; scale = 1.f;    dst = WoT; }
    if ((int)blockIdx.y * 64 >= N) return;

    const int tid = threadIdx.x;
    const int k0 = blockIdx.x * 64;
    const int n0 = blockIdx.y * 64;
    {
        int r = tid >> 2, c0 = (tid & 3) * 16;
        const float* sp = src + (size_t)(k0 + r) * N + n0 + c0;
        float4 v0 = *(const float4*)(sp + 0);
        float4 v1 = *(const float4*)(sp + 4);
        float4 v2 = *(const float4*)(sp + 8);
        float4 v3 = *(const float4*)(sp + 12);
        u16x8 s0 = { f2bf(v0.x * scale), f2bf(v0.y * scale), f2bf(v0.z * scale), f2bf(v0.w * scale),
                     f2bf(v1.x * scale), f2bf(v1.y * scale), f2bf(v1.z * scale), f2bf(v1.w * scale) };
        u16x8 s1 = { f2bf(v2.x * scale), f2bf(v2.y * scale), f2bf(v2.z * scale), f2bf(v2.w * scale),
                     f2bf(v3.x * scale), f2bf(v3.y * scale), f2bf(v3.z * scale), f2bf(v3.w * scale) };
        *(u16x8*)&tile[r][c0]     = s0;
        *(u16x8*)&tile[r][c0 + 8] = s1;
    }
    __syncthreads();
    {
        int n = tid >> 2, j0 = (tid & 3) * 16;
        u16x8 o0, o1;
        #pragma unroll
        for (int i = 0; i < 8; ++i) o0[i] = tile[j0 + i][n];
        #pragma unroll
        for (int i = 0; i < 8; ++i) o1[i] = tile[j0 + 8 + i][n];
        u16* dp = dst + (size_t)(n0 + n) * 2048 + k0 + j0;
        *(u16x8*)dp       = o0;
        *(u16x8*)(dp + 8) = o1;
    }
}

// ================= GEMM core: 256 threads (4 waves, 2x2), block 128x128 =================
// per-wave 64x64, BK=64, XOR-swizzled conflict-free LDS, g2l16 staging.
__device__ __forceinline__ void gemm_core_256(const u16* __restrict__ Ag,
                                              const u16* __restrict__ Bg,
                                              u16 (*Al)[64], u16 (*Bl)[64],
                                              int lane, int w, f32x4 acc[4][4])
{
    const int wm = w >> 1, wn = w & 1;
    const int r8 = lane >> 3;             // row-within-8 of staging
    const int cs = (lane & 7) ^ r8;       // inverse-swizzled source chunk
    const u16* ag = Ag + (size_t)(w * 32 + r8) * 2048 + cs * 8;
    const u16* bg = Bg + (size_t)(w * 32 + r8) * 2048 + cs * 8;
    const int fr = lane & 15;
    const int hq = lane >> 4;

    for (int kb = 0; kb < 2048; kb += 64) {
        #pragma unroll
        for (int j = 0; j < 4; ++j)
            g2l16(ag + (size_t)(j * 8) * 2048 + kb, &Al[w * 32 + j * 8][0]);
        #pragma unroll
        for (int j = 0; j < 4; ++j)
            g2l16(bg + (size_t)(j * 8) * 2048 + kb, &Bl[w * 32 + j * 8][0]);
        __syncthreads();

        #pragma unroll
        for (int kk = 0; kk < 2; ++kk) {
            bf16x8 af[4], bfn[4];
            #pragma unroll
            for (int m = 0; m < 4; ++m) {
                int row = wm * 64 + m * 16 + fr;
                int pc = (kk * 4 + hq) ^ (row & 7);
                af[m] = ld_bf8(&Al[row][pc * 8]);
            }
            #pragma unroll
            for (int n = 0; n < 4; ++n) {
                int row = wn * 64 + n * 16 + fr;
                int pc = (kk * 4 + hq) ^ (row & 7);
                bfn[n] = ld_bf8(&Bl[row][pc * 8]);
            }
            #pragma unroll
            for (int m = 0; m < 4; ++m)
                #pragma unroll
                for (int n = 0; n < 4; ++n)
                    acc[m][n] = __builtin_amdgcn_mfma_f32_16x16x32_bf16(af[m], bfn[n], acc[m][n], 0, 0, 0);
        }
        __syncthreads();
    }
}

// ---------------- QKV GEMM + fused RoPE epilogue + fused V transpose ----------------
__global__ __launch_bounds__(256, 3)
void qkv_gemm(const u16* __restrict__ xb, const u16* __restrict__ Wt,
              const float2* __restrict__ tab,
              u16* __restrict__ Qb, u16* __restrict__ Kb, u16* __restrict__ Vt)
{
    __shared__ __align__(16) u16 Al[128][64];
    __shared__ __align__(16) u16 Bl[128][64];
    const int tid = threadIdx.x;
    const int lane = tid & 63;
    const int w = tid >> 6;
    const int wm = w >> 1, wn = w & 1;
    const int m0  = blockIdx.x * 128;
    const int n0g = blockIdx.y * 128;

    f32x4 acc[4][4] = {};
    gemm_core_256(xb + (size_t)m0 * 2048, Wt + (size_t)n0g * 2048, Al, Bl, lane, w, acc);

    const int hq = lane >> 4;
    const int c0 = lane & 15;
    const int colbase = n0g + wn * 64;         // multiple of 64
    const bool isV = (n0g >= 2560);
    const bool isQ = (n0g < 2048);

    #pragma unroll
    for (int m = 0; m < 4; ++m) {
        #pragma unroll
        for (int r = 0; r < 4; ++r) {
            int rw = m0 + wm * 64 + m * 16 + hq * 4 + r;
            int b = rw >> 11, t = rw & 2047;
            if (!isV) {
                #pragma unroll
                for (int np = 0; np < 2; ++np) {
                    int dp = np * 16 + c0;
                    float2 cs = tab[t * 32 + dp];
                    float x1 = acc[m][np][r];
                    float x2 = acc[m][np + 2][r];
                    float lo = x1 * cs.x - x2 * cs.y;
                    float hi = x2 * cs.x + x1 * cs.y;
                    if (isQ) {
                        int h = colbase >> 6;
                        size_t base = (((size_t)b * 32 + h) * 2048 + t) * 64 + dp;
                        Qb[base]      = f2bf(lo);
                        Qb[base + 32] = f2bf(hi);
                    } else {
                        int hk = (colbase - 2048) >> 6;
                        size_t base = (((size_t)b * 8 + hk) * 2048 + t) * 64 + dp;
                        Kb[base]      = f2bf(lo);
                        Kb[base + 32] = f2bf(hi);
                    }
                }
            } else {
                // write V TRANSPOSED: Vt[(b,hk,d,t)]
                #pragma unroll
                for (int n = 0; n < 4; ++n) {
                    int c2 = colbase + n * 16 + c0 - 2560;
                    int hk = c2 >> 6, d = c2 & 63;
                    Vt[(((size_t)b * 8 + hk) * 64 + d) * 2048 + t] = f2bf(acc[m][n][r]);
                }
            }
        }
    }
}

// ---------------- Output projection ----------------
__global__ __launch_bounds__(256, 3)
void out_gemm(const u16* __restrict__ A, const u16* __restrict__ Wt, float* __restrict__ C)
{
    __shared__ __align__(16) u16 Al[128][64];
    __shared__ __align__(16) u16 Bl[128][64];
    const int tid = threadIdx.x;
    const int lane = tid & 63;
    const int w = tid >> 6;
    const int wm = w >> 1, wn = w & 1;
    const int m0 = blockIdx.x * 128;
    const int n0 = blockIdx.y * 128;

    f32x4 acc[4][4] = {};
    gemm_core_256(A + (size_t)m0 * 2048, Wt + (size_t)n0 * 2048, Al, Bl, lane, w, acc);

    const int hq = lane >> 4;
    const int c0 = lane & 15;
    #pragma unroll
    for (int m = 0; m < 4; ++m) {
        #pragma unroll
        for (int n = 0; n < 4; ++n) {
            #pragma unroll
            for (int r = 0; r < 4; ++r) {
                int rw = m0 + wm * 64 + m * 16 + hq * 4 + r;
                int col = n0 + wn * 64 + n * 16 + c0;
                C[(size_t)rw * 2048 + col] = acc[m][n][r];
            }
        }
    }
}

// ---------------- Flash attention: 8 waves, QBLK=128, KVBLK=128 (2 verified sub-tiles) ----------
// Sync structure identical to the round-16/19 passing kernel: compute-from-LDS -> barrier ->
// write-LDS -> barrier. Each iteration covers TWO 64-key sub-tiles (Kl[jj]/Vl[jj] are exact
// copies of the verified 64-key layout) -> 2 barriers per 128 keys instead of per 64.
__global__ __launch_bounds__(512)
void attn_kernel(const u16* __restrict__ Qb, const u16* __restrict__ Kb,
                 const u16* __restrict__ Vt, u16* __restrict__ AO)
{
    __shared__ __align__(16) u16 Kl[2][64][64];  // XOR-swizzled 16B chunks
    __shared__ __align__(16) u16 Vl[2][64][64];  // Vl[jj][d][j], swizzled
    __shared__ __align__(16) u16 Pl[8][16][64];  // per-wave [q][k], swizzled

    const int tid = threadIdx.x;
    const int lane = tid & 63;
    const int w = tid >> 6;                 // 0..7
    const int q = lane & 15;
    const int hq = lane >> 4;
    const int q0 = q_tmap[blockIdx.y] * 128;   // balanced q-tile per CU quartet
    const int bh = blockIdx.x;                 // bh fast -> CU quartets span q-tiles
    const int b = bh >> 5, h = bh & 31;
    const int hk = h >> 2;
    const size_t qbase  = (size_t)bh * 2048 * 64;
    const size_t kvbase = ((size_t)b * 8 + hk) * 2048 * 64;

    // staging geometry (per 64-key sub-tile): 512 thr = 64 rows x 8 chunks
    const int sj = tid >> 3;                // row 0..63
    const int sc = tid & 7;                 // logical chunk
    const int sw = (sc ^ (sj & 7)) << 3;    // swizzled phys offset (u16 units)
    const int ca0 = ((hq    ) ^ (q & 7)) << 3;
    const int ca1 = ((hq + 4) ^ (q & 7)) << 3;

    bf16x8 qf0, qf1;
    {
        const u16* qp = Qb + qbase + (size_t)(q0 + w * 16 + q) * 64 + hq * 8;
        qf0 = ld_bf8(qp);
        qf1 = ld_bf8(qp + 32);
    }

    float mrun = -1e20f, lrun = 0.f;
    f32x4 o[4] = {};

    int kbeg = q0 - (WINDOW - 1);
    if (kbeg < 0) kbeg = 0;
    kbeg &= ~63;
    const int kend = q0 + 128;   // (kend-kbeg)/64 is always EVEN -> whole 128-chunks

    const int wrow_min = q0 + w * 16;
    const int wrow_max = wrow_min + 15;
    const int iq = wrow_min + q;

    // prologue: stage both sub-tiles of the first 128-key chunk
    #pragma unroll
    for (int jj = 0; jj < 2; ++jj) {
        const u16* kg = Kb + kvbase + (size_t)(kbeg + jj * 64 + sj) * 64 + sc * 8;
        u16x8 kr = *(const u16x8*)kg;
        const u16* vg = Vt + kvbase + (size_t)sj * 2048 + kbeg + jj * 64 + sc * 8;
        u16x8 vr = *(const u16x8*)vg;
        *(u16x8*)&Kl[jj][sj][sw] = kr;
        *(u16x8*)&Vl[jj][sj][sw] = vr;
    }
    __syncthreads();

    for (int k0 = kbeg; k0 < kend; k0 += 128) {
        const bool has_next = (k0 + 128 < kend);
        u16x8 krn0, krn1, vrn0, vrn1;
        if (has_next) {
            const u16* kg0 = Kb + kvbase + (size_t)(k0 + 128 + sj) * 64 + sc * 8;
            krn0 = *(const u16x8*)kg0;
            const u16* kg1 = Kb + kvbase + (size_t)(k0 + 192 + sj) * 64 + sc * 8;
            krn1 = *(const u16x8*)kg1;
            const u16* vg0 = Vt + kvbase + (size_t)sj * 2048 + k0 + 128 + sc * 8;
            vrn0 = *(const u16x8*)vg0;
            const u16* vg1 = Vt + kvbase + (size_t)sj * 2048 + k0 + 192 + sc * 8;
            vrn1 = *(const u16x8*)vg1;
        }

        #pragma unroll
        for (int jj = 0; jj < 2; ++jj) {
            const int k0i = k0 + jj * 64;
            bool active = (k0i <= wrow_max) && (k0i + 63 >= wrow_min - (WINDOW - 1));
            if (active) {
                f32x4 s[4];
                __builtin_amdgcn_s_setprio(1);
                #pragma unroll
                for (int nf = 0; nf < 4; ++nf) {
                    bf16x8 kb0 = ld_bf8(&Kl[jj][nf * 16 + q][ca0]);
                    bf16x8 kb1 = ld_bf8(&Kl[jj][nf * 16 + q][ca1]);
                    f32x4 a = {};
                    a = __builtin_amdgcn_mfma_f32_16x16x32_bf16(kb0, qf0, a, 0, 0, 0);
                    a = __builtin_amdgcn_mfma_f32_16x16x32_bf16(kb1, qf1, a, 0, 0, 0);
                    s[nf] = a;
                }
                __builtin_amdgcn_s_setprio(0);
                bool need_causal = (k0i + 63 > wrow_min);
                bool need_window = (wrow_max - k0i) >= WINDOW;
                if (need_causal || need_window) {
                    #pragma unroll
                    for (int nf = 0; nf < 4; ++nf) {
                        #pragma unroll
                        for (int r = 0; r < 4; ++r) {
                            int j = k0i + nf * 16 + hq * 4 + r;
                            bool ok = (j <= iq) && (iq - j < WINDOW);
                            if (!ok) s[nf][r] = -1e30f;
                        }
                    }
                }
                f32x4 m4 = __builtin_elementwise_max(
                    __builtin_elementwise_max(s[0], s[1]),
                    __builtin_elementwise_max(s[2], s[3]));
                float tmax = fmaxf(fmaxf(m4[0], m4[1]), fmaxf(m4[2], m4[3]));
                tmax = fmaxf(tmax, __shfl_xor(tmax, 16));
                tmax = fmaxf(tmax, __shfl_xor(tmax, 32));

                bool skip = __all(tmax <= mrun + 11.5f);
                float mnew = skip ? mrun : fmaxf(mrun, tmax);

                float tsum = 0.f;
                #pragma unroll
                for (int nf = 0; nf < 4; ++nf) {
                    float p0 = exp2f_raw(s[nf][0] - mnew);
                    float p1 = exp2f_raw(s[nf][1] - mnew);
                    float p2 = exp2f_raw(s[nf][2] - mnew);
                    float p3 = exp2f_raw(s[nf][3] - mnew);
                    tsum += (p0 + p1) + (p2 + p3);
                    u32x2 pw = { cvt_pk_bf16(p0, p1), cvt_pk_bf16(p2, p3) };
                    int cpw = (((2 * nf + (hq >> 1)) ^ (q & 7)) << 3) + ((hq & 1) << 2);
                    *(u32x2*)&Pl[w][q][cpw] = pw;
                }
                tsum += __shfl_xor(tsum, 16);
                tsum += __shfl_xor(tsum, 32);

                if (skip) {
                    lrun += tsum;
                } else {
                    float sc2 = exp2f_raw(mrun - mnew);
                    mrun = mnew;
                    lrun = lrun * sc2 + tsum;
                    #pragma unroll
                    for (int nf = 0; nf < 4; ++nf)
                        #pragma unroll
                        for (int r = 0; r < 4; ++r)
                            o[nf][r] *= sc2;
                }

                bf16x8 pa0 = ld_bf8(&Pl[w][q][ca0]);
                bf16x8 pa1 = ld_bf8(&Pl[w][q][ca1]);
                __builtin_amdgcn_s_setprio(1);
                #pragma unroll
                for (int nf = 0; nf < 4; ++nf) {
                    bf16x8 vb0 = ld_bf8(&Vl[jj][nf * 16 + q][ca0]);
                    bf16x8 vb1 = ld_bf8(&Vl[jj][nf * 16 + q][ca1]);
                    // SWAPPED: o[nf][r] = O[q][nf*16+hq*4+r]
                    o[nf] = __builtin_amdgcn_mfma_f32_16x16x32_bf16(vb0, pa0, o[nf], 0, 0, 0);
                    o[nf] = __builtin_amdgcn_mfma_f32_16x16x32_bf16(vb1, pa1, o[nf], 0, 0, 0);
                }
                __builtin_amdgcn_s_setprio(0);
            }
        }
        __syncthreads();   // all reads of Kl/Vl/Pl retired
        if (has_next) {
            *(u16x8*)&Kl[0][sj][sw] = krn0;
            *(u16x8*)&Kl[1][sj][sw] = krn1;
            *(u16x8*)&Vl[0][sj][sw] = vrn0;
            *(u16x8*)&Vl[1][sj][sw] = vrn1;
        }
        __syncthreads();   // writes visible
    }

    // epilogue: lane-local l; 4 contiguous d per nf -> u16x4 stores
    float linv = 1.f / lrun;
    const int i = q0 + w * 16 + q;
    u16* aorow = AO + ((size_t)b * 2048 + i) * 2048 + h * 64;
    #pragma unroll
    for (int nf = 0; nf < 4; ++nf) {
        u16x4v ov = { f2bf(o[nf][0] * linv), f2bf(o[nf][1] * linv),
                      f2bf(o[nf][2] * linv), f2bf(o[nf][3] * linv) };
        *(u16x4v*)(aorow + nf * 16 + hq * 4) = ov;
    }
}

extern "C" void kernel_launch(void* const* d_in, const int* in_sizes, int n_in,
                              void* d_out, int out_size, void* d_ws, size_t ws_size,
                              hipStream_t stream)
{
    const float* x  = (const float*)d_in[0];
    const float* Wq = (const float*)d_in[1];
    const float* Wk = (const float*)d_in[2];
    const float* Wv = (const float*)d_in[3];
    const float* Wo = (const float*)d_in[4];
    float* out = (float*)d_out;

    u16* Qb    = (u16*)d_ws;                              //  8,388,608
    u16* Kb    = Qb    + (size_t)8388608;                 //  2,097,152
    u16* Vt    = Kb    + (size_t)2097152;                 //  2,097,152  (b,hk,d,t)
    u16* AO    = Vt    + (size_t)2097152;                 //  8,388,608
    u16* xb    = AO    + (size_t)8388608;                 //  8,388,608
    u16* WqkvT = xb    + (size_t)8388608;                 //  6,291,456  [3072][2048]
    u16* WoT   = WqkvT + (size_t)6291456;                 //  4,194,304  [2048][2048]
    float2* tab = (float2*)(WoT + (size_t)4194304);       //  512KB

    convert_x<<<4096, 256, 0, stream>>>(x, xb);
    trans_conv_all<<<dim3(32, 32, 5), 256, 0, stream>>>(Wq, Wk, Wv, Wo, WqkvT, WoT, tab);

    qkv_gemm<<<dim3(32, 24), 256, 0, stream>>>(xb, WqkvT, tab, Qb, Kb, Vt);
    attn_kernel<<<dim3(64, 16), 512, 0, stream>>>(Qb, Kb, Vt, AO);
    out_gemm<<<dim3(32, 16), 256, 0, stream>>>(AO, WoT, out);
}